// Round 9
// baseline (427.389 us; speedup 1.0000x reference)
//
#include <hip/hip_runtime.h>
#include <hip/hip_bf16.h>

#define IN_F 4096
#define OUT_F 4096
#define CPN 81
#define OINV 2225   // 81^{-1} mod 4096
#define OB16 2832   // 2225*16 mod 4096: o-step per group

#define BMF 8       // batch rows per block
#define NCH 8       // chunks per block
#define CHUNK 512   // band-starts (and x cols) per chunk
#define SC4 148     // float4 staged per row per chunk (592 cols)
#define NLD 1184    // BMF*SC4 total float4 loads per chunk
#define XSTR 616    // x LDS stride in bf16 elems
#define RSTRF 8     // res stride in bf16 elems (16 B per o-row)

typedef __attribute__((ext_vector_type(4))) float f32x4;
typedef __attribute__((ext_vector_type(8))) short bf16x8;

__device__ __forceinline__ unsigned short f2bf(float f) {
  __hip_bfloat16 h = __float2bfloat16(f);
  return *reinterpret_cast<unsigned short*>(&h);
}
__device__ __forceinline__ float bf2f(unsigned short u) {
  unsigned int v = ((unsigned int)u) << 16;
  return *reinterpret_cast<float*>(&v);
}

// 12 named wf fragments for one chunk (4 groups x 3 K-steps) — static access only
struct WF {
  bf16x8 w0, w1, w2, w3, w4, w5, w6, w7, w8, w9, w10, w11;
};

// ---- prep: pack weight*mask into MFMA B-fragment order ----
__global__ void prep_wfrag(const float* __restrict__ w,
                           const float* __restrict__ mask,
                           unsigned short* __restrict__ wfrag) {
  int idx = blockIdx.x * 256 + threadIdx.x;   // 49152 threads
  int lane = idx & 63;
  int t = (idx >> 6) % 3;
  int g = idx / 192;
  int n = lane & 15;
  int kg = lane >> 4;
  int s = g * 16 + n;
  int o = (OINV * s) & 4095;
  unsigned short v8[8];
#pragma unroll
  for (int i = 0; i < 8; ++i) {
    int c = 32 * t + 8 * kg + i;
    int j = c - n;
    float v = 0.f;
    if (j >= 0 && j < CPN) {
      int col = (16 * g + c) & 4095;
      v = w[(size_t)o * IN_F + col] * mask[(size_t)o * IN_F + col];
    }
    v8[i] = f2bf(v);
  }
  *reinterpret_cast<bf16x8*>(wfrag + (size_t)idx * 8) =
      *reinterpret_cast<const bf16x8*>(v8);
}

// ---- fused: x ping-pong + wfrag register double-buffer across chunks ----
__global__ __launch_bounds__(512, 4) void sc_fused(
    const float* __restrict__ x, const float* __restrict__ bias,
    const unsigned short* __restrict__ wfrag, float* __restrict__ out) {
  __shared__ unsigned short res[4096 * RSTRF];   // 65536 B: [o][row] bf16
  __shared__ unsigned short xl[BMF * XSTR];      //  9856 B

  const int blk = blockIdx.x;        // 0..2047
  const int b0 = blk * BMF;
  const int tid = threadIdx.x;
  const int wave = tid >> 6;         // 0..7
  const int lane = tid & 63;
  const int ln = lane & 15;          // MFMA n index (s offset)
  const int lk = lane >> 4;          // k-group / D row quad
  const int oln = (OINV * ln) & 4095;
  const int q0 = blk & 7;            // stagger chunk order across blocks

  // hoisted staging coordinates (3 load slots per thread)
  const int i1 = tid + 512, i2 = tid + 1024;
  const int row0 = tid / SC4, c40 = tid - row0 * SC4;
  const int row1 = i1  / SC4, c41 = i1  - row1 * SC4;
  const int row2 = i2  / SC4, c42 = i2  - row2 * SC4;
  const bool v2 = (i2 < NLD);
  const float* xp0 = x + (size_t)(b0 + row0) * IN_F;
  const float* xp1 = x + (size_t)(b0 + row1) * IN_F;
  const float* xp2 = x + (size_t)(b0 + row2) * IN_F;
  unsigned short* xw0 = xl + row0 * XSTR + 4 * c40;
  unsigned short* xw1 = xl + row1 * XSTR + 4 * c41;
  unsigned short* xw2 = xl + row2 * XSTR + 4 * c42;

  auto loadx = [&](int q, float4& r0, float4& r1, float4& r2) {
    const int c0 = q * CHUNK;
    r0 = *reinterpret_cast<const float4*>(xp0 + ((c0 + 4 * c40) & 4095));
    r1 = *reinterpret_cast<const float4*>(xp1 + ((c0 + 4 * c41) & 4095));
    if (v2) r2 = *reinterpret_cast<const float4*>(xp2 + ((c0 + 4 * c42) & 4095));
  };
  auto loadwf = [&](int q) -> WF {
    const bf16x8* wf = reinterpret_cast<const bf16x8*>(wfrag)
                     + (size_t)(q * 32 + wave * 4) * 192 + lane;
    WF r;
    r.w0 = wf[0];   r.w1 = wf[64];  r.w2  = wf[128];
    r.w3 = wf[192]; r.w4 = wf[256]; r.w5  = wf[320];
    r.w6 = wf[384]; r.w7 = wf[448]; r.w8  = wf[512];
    r.w9 = wf[576]; r.w10 = wf[640]; r.w11 = wf[704];
    return r;
  };
  auto drain = [&](const float4& r0, const float4& r1, const float4& r2) {
    ushort4 h;
    h.x = f2bf(r0.x); h.y = f2bf(r0.y); h.z = f2bf(r0.z); h.w = f2bf(r0.w);
    *reinterpret_cast<ushort4*>(xw0) = h;
    h.x = f2bf(r1.x); h.y = f2bf(r1.y); h.z = f2bf(r1.z); h.w = f2bf(r1.w);
    *reinterpret_cast<ushort4*>(xw1) = h;
    if (v2) {
      h.x = f2bf(r2.x); h.y = f2bf(r2.y); h.z = f2bf(r2.z); h.w = f2bf(r2.w);
      *reinterpret_cast<ushort4*>(xw2) = h;
    }
  };
  // one 16x16 group: 3 ds_reads + 3 MFMA + res scatter
  auto grp = [&](int g, const unsigned short* ap,
                 bf16x8 b0f, bf16x8 b1f, bf16x8 b2f) {
    bf16x8 a0 = *reinterpret_cast<const bf16x8*>(ap);
    bf16x8 a1 = *reinterpret_cast<const bf16x8*>(ap + 32);
    bf16x8 a2 = *reinterpret_cast<const bf16x8*>(ap + 64);
    f32x4 acc = f32x4{0.f, 0.f, 0.f, 0.f};
    acc = __builtin_amdgcn_mfma_f32_16x16x32_bf16(a0, b0f, acc, 0, 0, 0);
    acc = __builtin_amdgcn_mfma_f32_16x16x32_bf16(a1, b1f, acc, 0, 0, 0);
    acc = __builtin_amdgcn_mfma_f32_16x16x32_bf16(a2, b2f, acc, 0, 0, 0);
    if (lk < 2) {                    // rows 0..7 (8..15 are dups)
      int o = (OB16 * g + oln) & 4095;
      ushort4 h;
      h.x = f2bf(acc[0]); h.y = f2bf(acc[1]);
      h.z = f2bf(acc[2]); h.w = f2bf(acc[3]);
      *reinterpret_cast<ushort4*>(res + o * RSTRF + 4 * lk) = h;
    }
  };
  auto compute = [&](int q, const WF& w) {
    const int gbase = q * 32 + wave * 4;
    const unsigned short* ap = xl + (ln & 7) * XSTR + 8 * lk + 16 * (wave * 4);
    grp(gbase + 0, ap,      w.w0, w.w1, w.w2);
    grp(gbase + 1, ap + 16, w.w3, w.w4, w.w5);
    grp(gbase + 2, ap + 32, w.w6, w.w7, w.w8);
    grp(gbase + 3, ap + 48, w.w9, w.w10, w.w11);
  };

  // prologue: chunk q0's wf + x in flight
  float4 xA0, xA1, xA2, xB0, xB1, xB2;
  WF WA = loadwf(q0);
  loadx(q0, xA0, xA1, xA2);

  for (int qq = 0; qq < NCH; qq += 2) {
    const int qa = (q0 + qq) & 7;
    const int qb = (q0 + qq + 1) & 7;
    const int qc = (q0 + qq + 2) & 7;

    WF WB = loadwf(qb);                    // next chunk's B operand...
    loadx(qb, xB0, xB1, xB2);              // ...and x, issued early
    __builtin_amdgcn_sched_barrier(0);     // pin: cannot sink below
    drain(xA0, xA1, xA2);
    __syncthreads();
    compute(qa, WA);                       // all operands resident
    __syncthreads();

    if (qq + 2 < NCH) {
      WA = loadwf(qc);
      loadx(qc, xA0, xA1, xA2);
    }
    __builtin_amdgcn_sched_barrier(0);
    drain(xB0, xB1, xB2);
    __syncthreads();
    compute(qb, WB);
    __syncthreads();
  }

  // ---- epilogue: out[b0+r][o] = res[o][r] + bias[o] ----
  // lane = (ol, j): b32 read at byte 16o+4j -> bank 4(o&7)+j: 2-way max.
  const int j  = lane & 3;          // row pair 2j, 2j+1
  const int ol = lane >> 2;         // 0..15 consecutive o
#pragma unroll 4
  for (int it = 0; it < 32; ++it) {
    int o = it * 128 + wave * 16 + ol;
    unsigned int v = *reinterpret_cast<const unsigned int*>(res + o * RSTRF + 2 * j);
    float b = bias[o];
    float lo = bf2f((unsigned short)(v & 0xffff)) + b;
    float hi = bf2f((unsigned short)(v >> 16)) + b;
    size_t base = (size_t)(b0 + 2 * j) * OUT_F + o;
    out[base]         = lo;
    out[base + OUT_F] = hi;
  }
}

extern "C" void kernel_launch(void* const* d_in, const int* in_sizes, int n_in,
                              void* d_out, int out_size, void* d_ws, size_t ws_size,
                              hipStream_t stream) {
  const float* x    = (const float*)d_in[0];
  const float* w    = (const float*)d_in[1];
  const float* bias = (const float*)d_in[2];
  const float* mask = (const float*)d_in[3];
  float* out = (float*)d_out;

  unsigned short* wfrag = (unsigned short*)d_ws;   // 786432 B

  const int B = in_sizes[0] / IN_F;                // 16384

  prep_wfrag<<<192, 256, 0, stream>>>(w, mask, wfrag);
  sc_fused<<<B / BMF, 512, 0, stream>>>(x, bias, wfrag, out);
}

// Round 10
// 159.014 us; speedup vs baseline: 2.6877x; 2.6877x over previous
//
#include <hip/hip_runtime.h>
#include <hip/hip_bf16.h>

#define IN_F 4096
#define OUT_F 4096
#define CPN 81
#define OINV 2225   // 81^{-1} mod 4096
#define OB16 2832   // 2225*16 mod 4096: o-step per group

#define BMF 8       // batch rows per block
#define NCH 8       // chunks per block
#define CHUNK 512   // band-starts (and x cols) per chunk
#define SC4 148     // float4 staged per row per chunk (592 cols)
#define NLD 1184    // BMF*SC4 total float4 loads per chunk
#define XSTR 616    // x LDS stride in bf16 elems
#define RSTRF 8     // res stride in bf16 elems (16 B per o-row)

typedef __attribute__((ext_vector_type(4))) float f32x4;
typedef __attribute__((ext_vector_type(8))) short bf16x8;

__device__ __forceinline__ unsigned short f2bf(float f) {
  __hip_bfloat16 h = __float2bfloat16(f);
  return *reinterpret_cast<unsigned short*>(&h);
}
__device__ __forceinline__ float bf2f(unsigned short u) {
  unsigned int v = ((unsigned int)u) << 16;
  return *reinterpret_cast<float*>(&v);
}

// ---- prep: pack weight*mask into MFMA B-fragment order ----
__global__ void prep_wfrag(const float* __restrict__ w,
                           const float* __restrict__ mask,
                           unsigned short* __restrict__ wfrag) {
  int idx = blockIdx.x * 256 + threadIdx.x;   // 49152 threads
  int lane = idx & 63;
  int t = (idx >> 6) % 3;
  int g = idx / 192;
  int n = lane & 15;
  int kg = lane >> 4;
  int s = g * 16 + n;
  int o = (OINV * s) & 4095;
  unsigned short v8[8];
#pragma unroll
  for (int i = 0; i < 8; ++i) {
    int c = 32 * t + 8 * kg + i;
    int j = c - n;
    float v = 0.f;
    if (j >= 0 && j < CPN) {
      int col = (16 * g + c) & 4095;
      v = w[(size_t)o * IN_F + col] * mask[(size_t)o * IN_F + col];
    }
    v8[i] = f2bf(v);
  }
  *reinterpret_cast<bf16x8*>(wfrag + (size_t)idx * 8) =
      *reinterpret_cast<const bf16x8*>(v8);
}

// ---- fused: x ping-pong + batch-issued wfrag loads per chunk ----
__global__ __launch_bounds__(512, 4) void sc_fused(
    const float* __restrict__ x, const float* __restrict__ bias,
    const unsigned short* __restrict__ wfrag, float* __restrict__ out) {
  __shared__ unsigned short res[4096 * RSTRF];   // 65536 B: [o][row] bf16
  __shared__ unsigned short xl[BMF * XSTR];      //  9856 B

  const int blk = blockIdx.x;        // 0..2047
  const int b0 = blk * BMF;
  const int tid = threadIdx.x;
  const int wave = tid >> 6;         // 0..7
  const int lane = tid & 63;
  const int ln = lane & 15;          // MFMA n index (s offset)
  const int lk = lane >> 4;          // k-group / D row quad
  const int oln = (OINV * ln) & 4095;
  const int q0 = blk & 7;            // stagger chunk order across blocks

  // hoisted staging coordinates (3 load slots per thread)
  const int i1 = tid + 512, i2 = tid + 1024;
  const int row0 = tid / SC4, c40 = tid - row0 * SC4;
  const int row1 = i1  / SC4, c41 = i1  - row1 * SC4;
  const int row2 = i2  / SC4, c42 = i2  - row2 * SC4;
  const bool v2 = (i2 < NLD);
  const float* xp0 = x + (size_t)(b0 + row0) * IN_F;
  const float* xp1 = x + (size_t)(b0 + row1) * IN_F;
  const float* xp2 = x + (size_t)(b0 + row2) * IN_F;
  unsigned short* xw0 = xl + row0 * XSTR + 4 * c40;
  unsigned short* xw1 = xl + row1 * XSTR + 4 * c41;
  unsigned short* xw2 = xl + row2 * XSTR + 4 * c42;

  auto loadx = [&](int q, float4& r0, float4& r1, float4& r2) {
    const int c0 = q * CHUNK;
    r0 = *reinterpret_cast<const float4*>(xp0 + ((c0 + 4 * c40) & 4095));
    r1 = *reinterpret_cast<const float4*>(xp1 + ((c0 + 4 * c41) & 4095));
    if (v2) r2 = *reinterpret_cast<const float4*>(xp2 + ((c0 + 4 * c42) & 4095));
  };
  auto drain = [&](const float4& r0, const float4& r1, const float4& r2) {
    ushort4 h;
    h.x = f2bf(r0.x); h.y = f2bf(r0.y); h.z = f2bf(r0.z); h.w = f2bf(r0.w);
    *reinterpret_cast<ushort4*>(xw0) = h;
    h.x = f2bf(r1.x); h.y = f2bf(r1.y); h.z = f2bf(r1.z); h.w = f2bf(r1.w);
    *reinterpret_cast<ushort4*>(xw1) = h;
    if (v2) {
      h.x = f2bf(r2.x); h.y = f2bf(r2.y); h.z = f2bf(r2.z); h.w = f2bf(r2.w);
      *reinterpret_cast<ushort4*>(xw2) = h;
    }
  };
  // one 16x16 group: 3 ds_reads + 3 MFMA + res scatter
  auto grp = [&](int g, const unsigned short* ap,
                 bf16x8 b0f, bf16x8 b1f, bf16x8 b2f) {
    bf16x8 a0 = *reinterpret_cast<const bf16x8*>(ap);
    bf16x8 a1 = *reinterpret_cast<const bf16x8*>(ap + 32);
    bf16x8 a2 = *reinterpret_cast<const bf16x8*>(ap + 64);
    f32x4 acc = f32x4{0.f, 0.f, 0.f, 0.f};
    acc = __builtin_amdgcn_mfma_f32_16x16x32_bf16(a0, b0f, acc, 0, 0, 0);
    acc = __builtin_amdgcn_mfma_f32_16x16x32_bf16(a1, b1f, acc, 0, 0, 0);
    acc = __builtin_amdgcn_mfma_f32_16x16x32_bf16(a2, b2f, acc, 0, 0, 0);
    if (lk < 2) {                    // rows 0..7 (8..15 are dups)
      int o = (OB16 * g + oln) & 4095;
      ushort4 h;
      h.x = f2bf(acc[0]); h.y = f2bf(acc[1]);
      h.z = f2bf(acc[2]); h.w = f2bf(acc[3]);
      *reinterpret_cast<ushort4*>(res + o * RSTRF + 4 * lk) = h;
    }
  };
  auto compute = [&](int q) {
    const int gbase = q * 32 + wave * 4;
    const bf16x8* wf = reinterpret_cast<const bf16x8*>(wfrag)
                     + (size_t)gbase * 192 + lane;
    // batch-issue ALL 12 B-fragment loads (independent; mostly L2-resident):
    // the VMEM queue pipelines them; groups 2-4's loads land under compute.
    bf16x8 w0 = wf[0],   w1 = wf[64],  w2  = wf[128];
    bf16x8 w3 = wf[192], w4 = wf[256], w5  = wf[320];
    bf16x8 w6 = wf[384], w7 = wf[448], w8  = wf[512];
    bf16x8 w9 = wf[576], w10 = wf[640], w11 = wf[704];
    const unsigned short* ap = xl + (ln & 7) * XSTR + 8 * lk + 16 * (wave * 4);
    grp(gbase + 0, ap,      w0, w1, w2);
    grp(gbase + 1, ap + 16, w3, w4, w5);
    grp(gbase + 2, ap + 32, w6, w7, w8);
    grp(gbase + 3, ap + 48, w9, w10, w11);
  };

  // ping-pong x register sets A/B; loads pinned early by sched_barrier(0)
  float4 xA0, xA1, xA2, xB0, xB1, xB2;
  loadx(q0, xA0, xA1, xA2);

  for (int qq = 0; qq < NCH; qq += 2) {
    const int qa = (q0 + qq) & 7;
    const int qb = (q0 + qq + 1) & 7;

    loadx(qb, xB0, xB1, xB2);              // issue early...
    __builtin_amdgcn_sched_barrier(0);     // ...and pin: cannot sink below
    drain(xA0, xA1, xA2);
    __syncthreads();
    compute(qa);
    __syncthreads();

    if (qq + 2 < NCH) {
      loadx((q0 + qq + 2) & 7, xA0, xA1, xA2);
      __builtin_amdgcn_sched_barrier(0);
    }
    drain(xB0, xB1, xB2);
    __syncthreads();
    compute(qb);
    __syncthreads();
  }

  // ---- epilogue: out[b0+r][o] = res[o][r] + bias[o] ----
  // lane = (ol, j): b32 read at byte 16o+4j -> bank 4(o&7)+j: 2-way max.
  const int j  = lane & 3;          // row pair 2j, 2j+1
  const int ol = lane >> 2;         // 0..15 consecutive o
#pragma unroll 4
  for (int it = 0; it < 32; ++it) {
    int o = it * 128 + wave * 16 + ol;
    unsigned int v = *reinterpret_cast<const unsigned int*>(res + o * RSTRF + 2 * j);
    float b = bias[o];
    float lo = bf2f((unsigned short)(v & 0xffff)) + b;
    float hi = bf2f((unsigned short)(v >> 16)) + b;
    size_t base = (size_t)(b0 + 2 * j) * OUT_F + o;
    out[base]         = lo;
    out[base + OUT_F] = hi;
  }
}

extern "C" void kernel_launch(void* const* d_in, const int* in_sizes, int n_in,
                              void* d_out, int out_size, void* d_ws, size_t ws_size,
                              hipStream_t stream) {
  const float* x    = (const float*)d_in[0];
  const float* w    = (const float*)d_in[1];
  const float* bias = (const float*)d_in[2];
  const float* mask = (const float*)d_in[3];
  float* out = (float*)d_out;

  unsigned short* wfrag = (unsigned short*)d_ws;   // 786432 B

  const int B = in_sizes[0] / IN_F;                // 16384

  prep_wfrag<<<192, 256, 0, stream>>>(w, mask, wfrag);
  sc_fused<<<B / BMF, 512, 0, stream>>>(x, bias, wfrag, out);
}